// Round 6
// baseline (401.918 us; speedup 1.0000x reference)
//
#include <hip/hip_runtime.h>
#include <cstddef>

#define NN 100000
#define EE 1600000
#define FF 128
#define BSH 9                        // 512 nodes per bucket
#define NB ((NN + 511) / 512)        // 196 buckets
#define EPB 2048                     // edges per binscatter block (782 blocks)
#define HEPB 4096                    // edges per hist block (391 hist blocks)
#define DMAX 40                      // max degree handled by sort (P(exceed)~2e-7; skip = still correct)

typedef unsigned int uint;
typedef unsigned short ushort;
typedef short short8 __attribute__((ext_vector_type(8)));
typedef float f32x4 __attribute__((ext_vector_type(4)));

__device__ __forceinline__ ushort f2bf(float f) {
  uint u = __float_as_uint(f);
  uint r = u + 0x7fffu + ((u >> 16) & 1u);   // RNE
  return (ushort)(r >> 16);
}
__device__ __forceinline__ uint pack2(float a, float b) {
  return (uint)f2bf(a) | ((uint)f2bf(b) << 16);
}
// accumulate 8 bf16 (one uint4) into 8 fp32
__device__ __forceinline__ void acc8(float* a, uint4 v) {
  a[0] += __uint_as_float(v.x << 16);
  a[1] += __uint_as_float(v.x & 0xffff0000u);
  a[2] += __uint_as_float(v.y << 16);
  a[3] += __uint_as_float(v.y & 0xffff0000u);
  a[4] += __uint_as_float(v.z << 16);
  a[5] += __uint_as_float(v.z & 0xffff0000u);
  a[6] += __uint_as_float(v.w << 16);
  a[7] += __uint_as_float(v.w & 0xffff0000u);
}

// ---- fused converts + bucket histogram (heterogeneous grid) ----
__global__ __launch_bounds__(256) void cvt_hist(const float4* __restrict__ x,
                                                uint4* __restrict__ xb,
                                                const float* __restrict__ w0,
                                                ushort* __restrict__ wt0,
                                                const float* __restrict__ w1,
                                                ushort* __restrict__ wt1,
                                                const int* __restrict__ ei,
                                                int* __restrict__ btot) {
  __shared__ int h[NB];
  const int b = blockIdx.x;
  const int t = threadIdx.x;
  if (b < 6250) {
    int i = b * 256 + t;
    if (i >= NN * FF / 8) return;
    float4 a = x[2 * i];
    float4 c = x[2 * i + 1];
    uint4 o;
    o.x = pack2(a.x, a.y);
    o.y = pack2(a.z, a.w);
    o.z = pack2(c.x, c.y);
    o.w = pack2(c.z, c.w);
    xb[i] = o;
  } else if (b < 6378) {
    int i = (b - 6250) * 256 + t;        // 0..32767
    const float* w = (i < 16384) ? w0 : w1;
    ushort* wt = (i < 16384) ? wt0 : wt1;
    int j = i & 16383;
    int k = j >> 7, n = j & 127;
    wt[n * FF + k] = f2bf(w[(size_t)k * FF + n]);
  } else {
    const int hb = b - 6378;             // 0..390
    for (int i = t; i < NB; i += 256) h[i] = 0;
    __syncthreads();
    const int e0 = hb * HEPB + t;
#pragma unroll
    for (int i = 0; i < 16; ++i) {
      int e = e0 + i * 256;
      if (e < EE) atomicAdd(&h[ei[EE + e] >> BSH], 1);
    }
    __syncthreads();
    for (int i = t; i < NB; i += 256)
      if (h[i]) atomicAdd(&btot[i], h[i]);
  }
}

// ---------------- scan 196 bucket totals -> bases (one block) ----------------
__global__ __launch_bounds__(256) void bucket_scan(const int* __restrict__ btot,
                                                   int* __restrict__ bbase,
                                                   int* __restrict__ bcur,
                                                   int* __restrict__ offsets) {
  __shared__ int sd[256];
  const int t = threadIdx.x;
  sd[t] = (t < NB) ? btot[t] : 0;
  __syncthreads();
  for (int off = 1; off < 256; off <<= 1) {
    int v = 0;
    if (t >= off) v = sd[t - off];
    __syncthreads();
    if (t >= off) sd[t] += v;
    __syncthreads();
  }
  if (t < NB) {
    int b = t ? sd[t - 1] : 0;
    bbase[t] = b;
    bcur[t] = b;
  }
  if (t == 0) {
    bbase[NB] = EE;
    offsets[NN] = EE;
  }
}

// ---- binscatter: LDS counting-sort 2048 edges by bucket, coalesced dump ----
__global__ __launch_bounds__(256) void binscatter(const int* __restrict__ ei,
                                                  int* __restrict__ bcur,
                                                  uint2* __restrict__ pairs) {
  __shared__ uint2 lpair[EPB];     // 16 KB
  __shared__ int hcnt[256];        // hist, then local scatter cursor
  __shared__ int hincl[256];       // inclusive scan over buckets
  __shared__ int hbase[256];       // global base per bucket
  const int t = threadIdx.x;
  const int e0 = blockIdx.x * EPB;

  hcnt[t] = 0;
  __syncthreads();

  int es[8], ed[8];
#pragma unroll
  for (int i = 0; i < 8; ++i) {
    int e = e0 + t + i * 256;
    if (e < EE) {
      es[i] = ei[e];
      ed[i] = ei[EE + e];
      atomicAdd(&hcnt[ed[i] >> BSH], 1);
    } else {
      es[i] = -1;
      ed[i] = 0;
    }
  }
  __syncthreads();

  const int mycnt = hcnt[t];
  hincl[t] = mycnt;
  __syncthreads();
  for (int off = 1; off < 256; off <<= 1) {
    int tv = 0;
    if (t >= off) tv = hincl[t - off];
    __syncthreads();
    if (t >= off) hincl[t] += tv;
    __syncthreads();
  }
  if (t < NB && mycnt > 0) hbase[t] = atomicAdd(&bcur[t], mycnt);
  const int lbase = hincl[t] - mycnt;
  __syncthreads();
  hcnt[t] = lbase;                 // becomes local scatter cursor
  __syncthreads();

#pragma unroll
  for (int i = 0; i < 8; ++i) {
    if (es[i] >= 0) {
      int b = ed[i] >> BSH;
      int pos = atomicAdd(&hcnt[b], 1);
      lpair[pos] = make_uint2((uint)es[i], (uint)ed[i]);
    }
  }
  __syncthreads();

  const int total = hincl[255];
  for (int i = t; i < total; i += 256) {
    uint2 p = lpair[i];
    int b = (int)(p.y >> BSH);     // bucket id directly from dst
    int lb = b ? hincl[b - 1] : 0;
    pairs[(size_t)hbase[b] + (i - lb)] = p;
  }
}

// ---- fill2: one block per bucket. Counts its 512 nodes in LDS, scans,
//      writes per-node offsets, then scatters csr with LDS cursors. ----
__global__ __launch_bounds__(512) void fill2(const uint2* __restrict__ pairs,
                                             const int* __restrict__ bbase,
                                             int* __restrict__ offsets,
                                             int* __restrict__ csr) {
  __shared__ int cnt[512];
  __shared__ int cur[512];
  const int t = threadIdx.x;
  const int b = blockIdx.x;
  const int v0 = b << BSH;
  cnt[t] = 0;
  __syncthreads();
  const int pbeg = bbase[b];
  const int pend = bbase[b + 1];
  for (int j = pbeg + t; j < pend; j += 512)
    atomicAdd(&cnt[(int)pairs[j].y - v0], 1);
  __syncthreads();
  const int my = cnt[t];
  cur[t] = my;
  __syncthreads();
  for (int off = 1; off < 512; off <<= 1) {
    int v = 0;
    if (t >= off) v = cur[t - off];
    __syncthreads();
    if (t >= off) cur[t] += v;
    __syncthreads();
  }
  const int goff = pbeg + cur[t] - my;
  const int v = v0 + t;
  if (v < NN) offsets[v] = goff;
  __syncthreads();
  cur[t] = goff;
  __syncthreads();
  for (int j = pbeg + t; j < pend; j += 512) {
    uint2 p = pairs[j];
    int pos = atomicAdd(&cur[(int)p.y - v0], 1);
    csr[pos] = (int)p.x;
  }
}

// ---- sort_csr: per-node insertion sort of adjacency list by src index ----
// Pure performance hint for the gathers: sorted lists make all concurrently-
// executing nodes sweep the src space together -> L2-resident moving window.
// Thread-per-node, private LDS column buf[i*256+t] (conflict-free, no sync).
// deg > DMAX (P ~ 2e-7) is skipped -> still correct, just unsorted.
__global__ __launch_bounds__(256) void sort_csr(const int* __restrict__ offsets,
                                                int* __restrict__ csr) {
  __shared__ int buf[DMAX * 256];    // 40 KB
  const int t = threadIdx.x;
  const int g = blockIdx.x * 256 + t;
  if (g >= NN) return;
  const int beg = offsets[g];
  const int d = offsets[g + 1] - beg;
  if (d <= 1 || d > DMAX) return;
  for (int i = 0; i < d; ++i) buf[i * 256 + t] = csr[beg + i];
  for (int i = 1; i < d; ++i) {
    int key = buf[i * 256 + t];
    int j = i - 1;
    while (j >= 0 && buf[j * 256 + t] > key) {
      buf[(j + 1) * 256 + t] = buf[j * 256 + t];
      --j;
    }
    buf[(j + 1) * 256 + t] = key;
  }
  for (int i = 0; i < d; ++i) csr[beg + i] = buf[i * 256 + t];
}

// ---------------- gather-reduce (bf16 rows -> bf16 rows) ----------------
// round-1 proven version: unroll-4, VGPR 24, occupancy ~69%
__global__ __launch_bounds__(256) void gather_bf16(const uint4* __restrict__ feat,
                                                   const int* __restrict__ offsets,
                                                   const int* __restrict__ csr,
                                                   ushort* __restrict__ out) {
  int t = blockIdx.x * 256 + threadIdx.x;
  int g = t >> 4;
  int l = t & 15;
  if (g >= NN) return;
  int beg = offsets[g];
  int end = offsets[g + 1];
  float acc[8] = {};
  acc8(acc, feat[(size_t)g * 16 + l]);           // self term
  int j = beg;
  for (; j + 4 <= end; j += 4) {
    int i0 = csr[j], i1 = csr[j + 1], i2 = csr[j + 2], i3 = csr[j + 3];
    uint4 v0 = feat[(size_t)i0 * 16 + l];
    uint4 v1 = feat[(size_t)i1 * 16 + l];
    uint4 v2 = feat[(size_t)i2 * 16 + l];
    uint4 v3 = feat[(size_t)i3 * 16 + l];
    acc8(acc, v0); acc8(acc, v1); acc8(acc, v2); acc8(acc, v3);
  }
  for (; j < end; ++j) acc8(acc, feat[(size_t)csr[j] * 16 + l]);
  uint4 o;
  o.x = pack2(acc[0], acc[1]);
  o.y = pack2(acc[2], acc[3]);
  o.z = pack2(acc[4], acc[5]);
  o.w = pack2(acc[6], acc[7]);
  ((uint4*)(out + (size_t)g * FF))[l] = o;
}

// ---------------- bf16 MFMA GEMM (no LDS) ----------------
template <bool BN, bool OUT16>
__global__ __launch_bounds__(256) void gemm_mfma(const ushort* __restrict__ a,
    const ushort* __restrict__ bt, const float* __restrict__ bias,
    const float* __restrict__ gamma, const float* __restrict__ beta,
    const float* __restrict__ rmean, const float* __restrict__ rvar,
    void* __restrict__ out0, int nrows)
{
  const int tid = threadIdx.x;
  const int wv = tid >> 6;
  const int l = tid & 63;
  const int lane16 = l & 15;
  const int quad = l >> 4;
  const int rowbase = blockIdx.x * 128 + wv * 32;

  f32x4 acc[2][8] = {};

  for (int kc = 0; kc < FF; kc += 32) {
    short8 af[2];
#pragma unroll
    for (int rt = 0; rt < 2; ++rt) {
      int r = min(rowbase + rt * 16 + lane16, nrows - 1);
      af[rt] = *(const short8*)(a + (size_t)r * FF + kc + quad * 8);
    }
#pragma unroll
    for (int ct = 0; ct < 8; ++ct) {
      int n = ct * 16 + lane16;
      short8 bf = *(const short8*)(bt + n * FF + kc + quad * 8);
      acc[0][ct] = __builtin_amdgcn_mfma_f32_16x16x32_bf16(af[0], bf, acc[0][ct], 0, 0, 0);
      acc[1][ct] = __builtin_amdgcn_mfma_f32_16x16x32_bf16(af[1], bf, acc[1][ct], 0, 0, 0);
    }
  }

  float sc[8], sh[8];
#pragma unroll
  for (int ct = 0; ct < 8; ++ct) {
    int c = ct * 16 + lane16;
    if (BN) {
      float s = gamma[c] * rsqrtf(rvar[c] + 1e-5f);
      sc[ct] = s;
      sh[ct] = (bias[c] - rmean[c]) * s + beta[c];
    } else {
      sc[ct] = 1.0f;
      sh[ct] = bias[c];
    }
  }

#pragma unroll
  for (int rt = 0; rt < 2; ++rt) {
#pragma unroll
    for (int reg = 0; reg < 4; ++reg) {
      int r = rowbase + rt * 16 + quad * 4 + reg;
      if (r < nrows) {
#pragma unroll
        for (int ct = 0; ct < 8; ++ct) {
          int c = ct * 16 + lane16;
          float v = fmaf(acc[rt][ct][reg], sc[ct], sh[ct]);
          if (BN) v = fmaxf(v, 0.0f);
          if (OUT16) ((ushort*)out0)[(size_t)r * FF + c] = f2bf(v);
          else       ((float*)out0)[(size_t)r * FF + c] = v;
        }
      }
    }
  }
}

extern "C" void kernel_launch(void* const* d_in, const int* in_sizes, int n_in,
                              void* d_out, int out_size, void* d_ws, size_t ws_size,
                              hipStream_t stream) {
  const float* x     = (const float*)d_in[0];
  const int*   ei    = (const int*)d_in[1];
  const float* w0    = (const float*)d_in[2];
  const float* b0    = (const float*)d_in[3];
  const float* gamma = (const float*)d_in[4];
  const float* beta  = (const float*)d_in[5];
  const float* rmean = (const float*)d_in[6];
  const float* rvar  = (const float*)d_in[7];
  const float* w1    = (const float*)d_in[8];
  const float* b1    = (const float*)d_in[9];
  float* out = (float*)d_out;

  // workspace layout
  ushort* sb  = (ushort*)d_ws;                    // NN*FF
  ushort* xb  = sb + (size_t)NN * FF;             // NN*FF
  ushort* hb  = xb + (size_t)NN * FF;             // NN*FF
  ushort* wt0 = hb + (size_t)NN * FF;             // 128*128
  ushort* wt1 = wt0 + FF * FF;                    // 128*128
  uint2* pairs  = (uint2*)(wt1 + FF * FF);        // EE uint2 (12.8 MB)
  int* csr      = (int*)(pairs + (size_t)EE);     // EE
  int* offsets  = csr + EE;                       // NN+1
  int* bcur     = offsets + NN + 1;               // NB
  int* bbase    = bcur + NB;                      // NB+1
  int* btot     = bbase + NB + 1;                 // NB

  const int gatherb = (NN * 16 + 255) / 256;      // 6250
  const int gemmb = (NN + 127) / 128;             // 782
  const int binb = (EE + EPB - 1) / EPB;          // 782
  const int sortb = (NN + 255) / 256;             // 391
  const int cvb = 6250 + 128 + 391;               // 6769

  // ---- converts + hist (fused), then CSR build ----
  (void)hipMemsetAsync(btot, 0, (size_t)NB * sizeof(int), stream);
  cvt_hist<<<cvb, 256, 0, stream>>>((const float4*)x, (uint4*)xb, w0, wt0,
                                    w1, wt1, ei, btot);
  bucket_scan<<<1, 256, 0, stream>>>(btot, bbase, bcur, offsets);
  binscatter<<<binb, 256, 0, stream>>>(ei, bcur, pairs);
  fill2<<<NB, 512, 0, stream>>>(pairs, bbase, offsets, csr);
  sort_csr<<<sortb, 256, 0, stream>>>(offsets, csr);

  // ---- layer 1 ----
  gather_bf16<<<gatherb, 256, 0, stream>>>((const uint4*)xb, offsets, csr, sb);
  gemm_mfma<true, true><<<gemmb, 256, 0, stream>>>(sb, wt0, b0, gamma, beta,
                                                   rmean, rvar, (void*)hb, NN);
  // ---- layer 2 ----
  gather_bf16<<<gatherb, 256, 0, stream>>>((const uint4*)hb, offsets, csr, sb);
  gemm_mfma<false, false><<<gemmb, 256, 0, stream>>>(sb, wt1, b1, nullptr, nullptr,
                                                     nullptr, nullptr, (void*)out, NN);
}

// Round 7
// 354.086 us; speedup vs baseline: 1.1351x; 1.1351x over previous
//
#include <hip/hip_runtime.h>
#include <cstddef>

#define NN 100000
#define EE 1600000
#define FF 128
#define BSH 9                        // 512 nodes per bucket
#define NB ((NN + 511) / 512)        // 196 buckets
#define EPB 2048                     // edges per binscatter block (782 blocks)
#define HEPB 4096                    // edges per hist block (391 hist blocks)
#define FMAX 10240                   // fill2 LDS staging cap (mean 8192, +4sigma ~8550)

typedef unsigned int uint;
typedef unsigned short ushort;
typedef short short8 __attribute__((ext_vector_type(8)));
typedef float f32x4 __attribute__((ext_vector_type(4)));

__device__ __forceinline__ ushort f2bf(float f) {
  uint u = __float_as_uint(f);
  uint r = u + 0x7fffu + ((u >> 16) & 1u);   // RNE
  return (ushort)(r >> 16);
}
__device__ __forceinline__ uint pack2(float a, float b) {
  return (uint)f2bf(a) | ((uint)f2bf(b) << 16);
}
// accumulate 8 bf16 (one uint4) into 8 fp32
__device__ __forceinline__ void acc8(float* a, uint4 v) {
  a[0] += __uint_as_float(v.x << 16);
  a[1] += __uint_as_float(v.x & 0xffff0000u);
  a[2] += __uint_as_float(v.y << 16);
  a[3] += __uint_as_float(v.y & 0xffff0000u);
  a[4] += __uint_as_float(v.z << 16);
  a[5] += __uint_as_float(v.z & 0xffff0000u);
  a[6] += __uint_as_float(v.w << 16);
  a[7] += __uint_as_float(v.w & 0xffff0000u);
}

// ---- fused converts + bucket histogram (heterogeneous grid) ----
__global__ __launch_bounds__(256) void cvt_hist(const float4* __restrict__ x,
                                                uint4* __restrict__ xb,
                                                const float* __restrict__ w0,
                                                ushort* __restrict__ wt0,
                                                const float* __restrict__ w1,
                                                ushort* __restrict__ wt1,
                                                const int* __restrict__ ei,
                                                int* __restrict__ btot) {
  __shared__ int h[NB];
  const int b = blockIdx.x;
  const int t = threadIdx.x;
  if (b < 6250) {
    int i = b * 256 + t;
    if (i >= NN * FF / 8) return;
    float4 a = x[2 * i];
    float4 c = x[2 * i + 1];
    uint4 o;
    o.x = pack2(a.x, a.y);
    o.y = pack2(a.z, a.w);
    o.z = pack2(c.x, c.y);
    o.w = pack2(c.z, c.w);
    xb[i] = o;
  } else if (b < 6378) {
    int i = (b - 6250) * 256 + t;        // 0..32767
    const float* w = (i < 16384) ? w0 : w1;
    ushort* wt = (i < 16384) ? wt0 : wt1;
    int j = i & 16383;
    int k = j >> 7, n = j & 127;
    wt[n * FF + k] = f2bf(w[(size_t)k * FF + n]);
  } else {
    const int hb = b - 6378;             // 0..390
    for (int i = t; i < NB; i += 256) h[i] = 0;
    __syncthreads();
    const int e0 = hb * HEPB + t;
#pragma unroll
    for (int i = 0; i < 16; ++i) {
      int e = e0 + i * 256;
      if (e < EE) atomicAdd(&h[ei[EE + e] >> BSH], 1);
    }
    __syncthreads();
    for (int i = t; i < NB; i += 256)
      if (h[i]) atomicAdd(&btot[i], h[i]);
  }
}

// ---- binscatter: LDS counting-sort 2048 edges by bucket, coalesced dump ----
// Computes bucket bases locally from btot (196-scan in LDS) -> no separate
// bucket_scan dispatch; bcur is a zero-based delta cursor (memset-zeroed).
__global__ __launch_bounds__(256) void binscatter(const int* __restrict__ ei,
                                                  const int* __restrict__ btot,
                                                  int* __restrict__ bcur,
                                                  uint2* __restrict__ pairs) {
  __shared__ uint2 lpair[EPB];     // 16 KB
  __shared__ int hcnt[256];        // hist, then local scatter cursor
  __shared__ int hincl[256];       // inclusive scan over buckets
  __shared__ int hbase[256];       // global base per bucket
  __shared__ int sdb[256];         // btot inclusive scan
  const int t = threadIdx.x;
  const int e0 = blockIdx.x * EPB;

  hcnt[t] = 0;
  sdb[t] = (t < NB) ? btot[t] : 0;
  __syncthreads();

  int es[8], ed[8];
#pragma unroll
  for (int i = 0; i < 8; ++i) {
    int e = e0 + t + i * 256;
    if (e < EE) {
      es[i] = ei[e];
      ed[i] = ei[EE + e];
      atomicAdd(&hcnt[ed[i] >> BSH], 1);
    } else {
      es[i] = -1;
      ed[i] = 0;
    }
  }
  // btot scan (dependency-free vs the staging loads above)
  for (int off = 1; off < 256; off <<= 1) {
    int v = 0;
    if (t >= off) v = sdb[t - off];
    __syncthreads();
    if (t >= off) sdb[t] += v;
    __syncthreads();
  }
  __syncthreads();

  const int mycnt = hcnt[t];
  hincl[t] = mycnt;
  __syncthreads();
  for (int off = 1; off < 256; off <<= 1) {
    int tv = 0;
    if (t >= off) tv = hincl[t - off];
    __syncthreads();
    if (t >= off) hincl[t] += tv;
    __syncthreads();
  }
  // reserve global range: local base from btot scan + delta cursor
  if (t < NB && mycnt > 0) {
    int gbase = t ? sdb[t - 1] : 0;
    hbase[t] = gbase + atomicAdd(&bcur[t], mycnt);
  }
  const int lbase = hincl[t] - mycnt;
  __syncthreads();
  hcnt[t] = lbase;                 // becomes local scatter cursor
  __syncthreads();

#pragma unroll
  for (int i = 0; i < 8; ++i) {
    if (es[i] >= 0) {
      int b = ed[i] >> BSH;
      int pos = atomicAdd(&hcnt[b], 1);
      lpair[pos] = make_uint2((uint)es[i], (uint)ed[i]);
    }
  }
  __syncthreads();

  const int total = hincl[255];
  for (int i = t; i < total; i += 256) {
    uint2 p = lpair[i];
    int b = (int)(p.y >> BSH);     // bucket id directly from dst
    int lb = b ? hincl[b - 1] : 0;
    pairs[(size_t)hbase[b] + (i - lb)] = p;
  }
}

// ---- fill2: one block per bucket, single-pass via LDS pair staging.
//      Computes its segment bounds locally from btot; counts its 512 nodes,
//      scans, writes offsets, scatters csr with LDS cursors. ----
__global__ __launch_bounds__(512) void fill2(const uint2* __restrict__ pairs,
                                             const int* __restrict__ btot,
                                             int* __restrict__ offsets,
                                             int* __restrict__ csr) {
  __shared__ uint2 lp[FMAX];       // 80 KB staged pairs
  __shared__ int cnt[512];
  __shared__ int cur[512];
  __shared__ int sdb[256];         // btot inclusive scan
  const int t = threadIdx.x;
  const int b = blockIdx.x;
  const int v0 = b << BSH;

  cnt[t] = 0;
  if (t < 256) sdb[t] = (t < NB) ? btot[t] : 0;
  __syncthreads();
  for (int off = 1; off < 256; off <<= 1) {
    int v = 0;
    if (t < 256 && t >= off) v = sdb[t - off];
    __syncthreads();
    if (t < 256 && t >= off) sdb[t] += v;
    __syncthreads();
  }
  const int pbeg = b ? sdb[b - 1] : 0;
  const int pend = sdb[b];
  const int m = pend - pbeg;
  const bool stage = (m <= FMAX);

  if (stage) {
    for (int j = t; j < m; j += 512) lp[j] = pairs[pbeg + j];
    __syncthreads();
    for (int j = t; j < m; j += 512)
      atomicAdd(&cnt[(int)lp[j].y - v0], 1);
  } else {
    for (int j = pbeg + t; j < pend; j += 512)
      atomicAdd(&cnt[(int)pairs[j].y - v0], 1);
  }
  __syncthreads();
  const int my = cnt[t];
  cur[t] = my;
  __syncthreads();
  for (int off = 1; off < 512; off <<= 1) {
    int v = 0;
    if (t >= off) v = cur[t - off];
    __syncthreads();
    if (t >= off) cur[t] += v;
    __syncthreads();
  }
  const int goff = pbeg + cur[t] - my;
  const int v = v0 + t;
  if (v < NN) offsets[v] = goff;
  if (b == 0 && t == 0) offsets[NN] = EE;
  __syncthreads();
  cur[t] = goff;
  __syncthreads();
  if (stage) {
    for (int j = t; j < m; j += 512) {
      uint2 p = lp[j];
      int pos = atomicAdd(&cur[(int)p.y - v0], 1);
      csr[pos] = (int)p.x;
    }
  } else {
    for (int j = pbeg + t; j < pend; j += 512) {
      uint2 p = pairs[j];
      int pos = atomicAdd(&cur[(int)p.y - v0], 1);
      csr[pos] = (int)p.x;
    }
  }
}

// ---------------- gather-reduce (bf16 rows -> bf16 rows) ----------------
// proven version: unroll-4, VGPR 24, occupancy ~69% — at the random-256B wall
__global__ __launch_bounds__(256) void gather_bf16(const uint4* __restrict__ feat,
                                                   const int* __restrict__ offsets,
                                                   const int* __restrict__ csr,
                                                   ushort* __restrict__ out) {
  int t = blockIdx.x * 256 + threadIdx.x;
  int g = t >> 4;
  int l = t & 15;
  if (g >= NN) return;
  int beg = offsets[g];
  int end = offsets[g + 1];
  float acc[8] = {};
  acc8(acc, feat[(size_t)g * 16 + l]);           // self term
  int j = beg;
  for (; j + 4 <= end; j += 4) {
    int i0 = csr[j], i1 = csr[j + 1], i2 = csr[j + 2], i3 = csr[j + 3];
    uint4 v0 = feat[(size_t)i0 * 16 + l];
    uint4 v1 = feat[(size_t)i1 * 16 + l];
    uint4 v2 = feat[(size_t)i2 * 16 + l];
    uint4 v3 = feat[(size_t)i3 * 16 + l];
    acc8(acc, v0); acc8(acc, v1); acc8(acc, v2); acc8(acc, v3);
  }
  for (; j < end; ++j) acc8(acc, feat[(size_t)csr[j] * 16 + l]);
  uint4 o;
  o.x = pack2(acc[0], acc[1]);
  o.y = pack2(acc[2], acc[3]);
  o.z = pack2(acc[4], acc[5]);
  o.w = pack2(acc[6], acc[7]);
  ((uint4*)(out + (size_t)g * FF))[l] = o;
}

// ---------------- bf16 MFMA GEMM (no LDS) ----------------
template <bool BN, bool OUT16>
__global__ __launch_bounds__(256) void gemm_mfma(const ushort* __restrict__ a,
    const ushort* __restrict__ bt, const float* __restrict__ bias,
    const float* __restrict__ gamma, const float* __restrict__ beta,
    const float* __restrict__ rmean, const float* __restrict__ rvar,
    void* __restrict__ out0, int nrows)
{
  const int tid = threadIdx.x;
  const int wv = tid >> 6;
  const int l = tid & 63;
  const int lane16 = l & 15;
  const int quad = l >> 4;
  const int rowbase = blockIdx.x * 128 + wv * 32;

  f32x4 acc[2][8] = {};

  for (int kc = 0; kc < FF; kc += 32) {
    short8 af[2];
#pragma unroll
    for (int rt = 0; rt < 2; ++rt) {
      int r = min(rowbase + rt * 16 + lane16, nrows - 1);
      af[rt] = *(const short8*)(a + (size_t)r * FF + kc + quad * 8);
    }
#pragma unroll
    for (int ct = 0; ct < 8; ++ct) {
      int n = ct * 16 + lane16;
      short8 bf = *(const short8*)(bt + n * FF + kc + quad * 8);
      acc[0][ct] = __builtin_amdgcn_mfma_f32_16x16x32_bf16(af[0], bf, acc[0][ct], 0, 0, 0);
      acc[1][ct] = __builtin_amdgcn_mfma_f32_16x16x32_bf16(af[1], bf, acc[1][ct], 0, 0, 0);
    }
  }

  float sc[8], sh[8];
#pragma unroll
  for (int ct = 0; ct < 8; ++ct) {
    int c = ct * 16 + lane16;
    if (BN) {
      float s = gamma[c] * rsqrtf(rvar[c] + 1e-5f);
      sc[ct] = s;
      sh[ct] = (bias[c] - rmean[c]) * s + beta[c];
    } else {
      sc[ct] = 1.0f;
      sh[ct] = bias[c];
    }
  }

#pragma unroll
  for (int rt = 0; rt < 2; ++rt) {
#pragma unroll
    for (int reg = 0; reg < 4; ++reg) {
      int r = rowbase + rt * 16 + quad * 4 + reg;
      if (r < nrows) {
#pragma unroll
        for (int ct = 0; ct < 8; ++ct) {
          int c = ct * 16 + lane16;
          float v = fmaf(acc[rt][ct][reg], sc[ct], sh[ct]);
          if (BN) v = fmaxf(v, 0.0f);
          if (OUT16) ((ushort*)out0)[(size_t)r * FF + c] = f2bf(v);
          else       ((float*)out0)[(size_t)r * FF + c] = v;
        }
      }
    }
  }
}

extern "C" void kernel_launch(void* const* d_in, const int* in_sizes, int n_in,
                              void* d_out, int out_size, void* d_ws, size_t ws_size,
                              hipStream_t stream) {
  const float* x     = (const float*)d_in[0];
  const int*   ei    = (const int*)d_in[1];
  const float* w0    = (const float*)d_in[2];
  const float* b0    = (const float*)d_in[3];
  const float* gamma = (const float*)d_in[4];
  const float* beta  = (const float*)d_in[5];
  const float* rmean = (const float*)d_in[6];
  const float* rvar  = (const float*)d_in[7];
  const float* w1    = (const float*)d_in[8];
  const float* b1    = (const float*)d_in[9];
  float* out = (float*)d_out;

  // workspace layout
  ushort* sb  = (ushort*)d_ws;                    // NN*FF
  ushort* xb  = sb + (size_t)NN * FF;             // NN*FF
  ushort* hb  = xb + (size_t)NN * FF;             // NN*FF
  ushort* wt0 = hb + (size_t)NN * FF;             // 128*128
  ushort* wt1 = wt0 + FF * FF;                    // 128*128
  uint2* pairs  = (uint2*)(wt1 + FF * FF);        // EE uint2 (12.8 MB)
  int* csr      = (int*)(pairs + (size_t)EE);     // EE
  int* offsets  = csr + EE;                       // NN+1
  int* btot     = offsets + NN + 1;               // NB
  int* bcur     = btot + NB;                      // NB (adjacent: one memset)

  const int gatherb = (NN * 16 + 255) / 256;      // 6250
  const int gemmb = (NN + 127) / 128;             // 782
  const int binb = (EE + EPB - 1) / EPB;          // 782
  const int cvb = 6250 + 128 + 391;               // 6769

  // ---- converts + hist (fused), then CSR build (no scan dispatch) ----
  (void)hipMemsetAsync(btot, 0, (size_t)(2 * NB) * sizeof(int), stream);
  cvt_hist<<<cvb, 256, 0, stream>>>((const float4*)x, (uint4*)xb, w0, wt0,
                                    w1, wt1, ei, btot);
  binscatter<<<binb, 256, 0, stream>>>(ei, btot, bcur, pairs);
  fill2<<<NB, 512, 0, stream>>>(pairs, btot, offsets, csr);

  // ---- layer 1 ----
  gather_bf16<<<gatherb, 256, 0, stream>>>((const uint4*)xb, offsets, csr, sb);
  gemm_mfma<true, true><<<gemmb, 256, 0, stream>>>(sb, wt0, b0, gamma, beta,
                                                   rmean, rvar, (void*)hb, NN);
  // ---- layer 2 ----
  gather_bf16<<<gatherb, 256, 0, stream>>>((const uint4*)hb, offsets, csr, sb);
  gemm_mfma<false, false><<<gemmb, 256, 0, stream>>>(sb, wt1, b1, nullptr, nullptr,
                                                     nullptr, nullptr, (void*)out, NN);
}

// Round 8
// 351.174 us; speedup vs baseline: 1.1445x; 1.0083x over previous
//
#include <hip/hip_runtime.h>
#include <cstddef>

#define NN 100000
#define EE 1600000
#define FF 128
#define BSH 9                        // 512 nodes per bucket
#define NB ((NN + 511) / 512)        // 196 buckets
#define EPB 2048                     // edges per binscatter block (782 blocks)
#define HEPB 4096                    // edges per hist block (391 hist blocks)
#define FMAX 10240                   // fill2 LDS staging cap (mean 8192, +4sigma ~8550)
#define BINB 782                     // binscatter blocks
#define XCB 6250                     // x-convert blocks
#define WCB 128                      // w-convert blocks

typedef unsigned int uint;
typedef unsigned short ushort;
typedef short short8 __attribute__((ext_vector_type(8)));
typedef float f32x4 __attribute__((ext_vector_type(4)));

__device__ __forceinline__ ushort f2bf(float f) {
  uint u = __float_as_uint(f);
  uint r = u + 0x7fffu + ((u >> 16) & 1u);   // RNE
  return (ushort)(r >> 16);
}
__device__ __forceinline__ uint pack2(float a, float b) {
  return (uint)f2bf(a) | ((uint)f2bf(b) << 16);
}
// accumulate 8 bf16 (one uint4) into 8 fp32
__device__ __forceinline__ void acc8(float* a, uint4 v) {
  a[0] += __uint_as_float(v.x << 16);
  a[1] += __uint_as_float(v.x & 0xffff0000u);
  a[2] += __uint_as_float(v.y << 16);
  a[3] += __uint_as_float(v.y & 0xffff0000u);
  a[4] += __uint_as_float(v.z << 16);
  a[5] += __uint_as_float(v.z & 0xffff0000u);
  a[6] += __uint_as_float(v.w << 16);
  a[7] += __uint_as_float(v.w & 0xffff0000u);
}

// ---------------- bucket histogram (196 bins, LDS-privatized) ----------------
// Standalone and FIRST: reads only dst (6.4 MB) so the CSR chain starts
// immediately; the 77 MB feature convert no longer serializes ahead of it.
__global__ __launch_bounds__(256) void bucket_hist(const int* __restrict__ ei,
                                                   int* __restrict__ btot) {
  __shared__ int h[NB];
  const int t = threadIdx.x;
  for (int i = t; i < NB; i += 256) h[i] = 0;
  __syncthreads();
  const int e0 = blockIdx.x * HEPB + t;
#pragma unroll
  for (int i = 0; i < 16; ++i) {
    int e = e0 + i * 256;
    if (e < EE) atomicAdd(&h[ei[EE + e] >> BSH], 1);
  }
  __syncthreads();
  for (int i = t; i < NB; i += 256)
    if (h[i]) atomicAdd(&btot[i], h[i]);
}

// ---- bin_cvt: heterogeneous grid ----
// blocks 0..781       : binscatter (CSR critical path, dispatched first)
// blocks 782..7031    : x -> bf16 convert (overlaps binscatter)
// blocks 7032..7159   : w0/w1 transpose-convert
// Union LDS = 20 KB -> 8 blocks/CU (= 2048-thread cap), so convert
// occupancy is not reduced by the fusion.
__global__ __launch_bounds__(256) void bin_cvt(const int* __restrict__ ei,
                                               const int* __restrict__ btot,
                                               int* __restrict__ bcur,
                                               uint2* __restrict__ pairs,
                                               const float4* __restrict__ x,
                                               uint4* __restrict__ xb,
                                               const float* __restrict__ w0,
                                               ushort* __restrict__ wt0,
                                               const float* __restrict__ w1,
                                               ushort* __restrict__ wt1) {
  __shared__ uint2 lpair[EPB];     // 16 KB
  __shared__ int hcnt[256];        // hist, then local scatter cursor
  __shared__ int hincl[256];       // inclusive scan over buckets
  __shared__ int hbase[256];       // global base per bucket
  __shared__ int sdb[256];         // btot inclusive scan
  const int b = blockIdx.x;
  const int t = threadIdx.x;

  if (b >= BINB) {
    if (b < BINB + XCB) {
      int i = (b - BINB) * 256 + t;
      if (i < NN * FF / 8) {
        float4 a = x[2 * i];
        float4 c = x[2 * i + 1];
        uint4 o;
        o.x = pack2(a.x, a.y);
        o.y = pack2(a.z, a.w);
        o.z = pack2(c.x, c.y);
        o.w = pack2(c.z, c.w);
        xb[i] = o;
      }
    } else {
      int i = (b - BINB - XCB) * 256 + t;     // 0..32767
      const float* w = (i < 16384) ? w0 : w1;
      ushort* wt = (i < 16384) ? wt0 : wt1;
      int j = i & 16383;
      int k = j >> 7, n = j & 127;
      wt[n * FF + k] = f2bf(w[(size_t)k * FF + n]);
    }
    return;
  }

  // ---------------- binscatter part (blocks 0..781) ----------------
  const int e0 = b * EPB;
  hcnt[t] = 0;
  sdb[t] = (t < NB) ? btot[t] : 0;
  __syncthreads();

  int es[8], ed[8];
#pragma unroll
  for (int i = 0; i < 8; ++i) {
    int e = e0 + t + i * 256;
    if (e < EE) {
      es[i] = ei[e];
      ed[i] = ei[EE + e];
      atomicAdd(&hcnt[ed[i] >> BSH], 1);
    } else {
      es[i] = -1;
      ed[i] = 0;
    }
  }
  // btot scan (dependency-free vs the staging loads above)
  for (int off = 1; off < 256; off <<= 1) {
    int v = 0;
    if (t >= off) v = sdb[t - off];
    __syncthreads();
    if (t >= off) sdb[t] += v;
    __syncthreads();
  }
  __syncthreads();

  const int mycnt = hcnt[t];
  hincl[t] = mycnt;
  __syncthreads();
  for (int off = 1; off < 256; off <<= 1) {
    int tv = 0;
    if (t >= off) tv = hincl[t - off];
    __syncthreads();
    if (t >= off) hincl[t] += tv;
    __syncthreads();
  }
  // reserve global range: local base from btot scan + delta cursor
  if (t < NB && mycnt > 0) {
    int gbase = t ? sdb[t - 1] : 0;
    hbase[t] = gbase + atomicAdd(&bcur[t], mycnt);
  }
  const int lbase = hincl[t] - mycnt;
  __syncthreads();
  hcnt[t] = lbase;                 // becomes local scatter cursor
  __syncthreads();

#pragma unroll
  for (int i = 0; i < 8; ++i) {
    if (es[i] >= 0) {
      int bb = ed[i] >> BSH;
      int pos = atomicAdd(&hcnt[bb], 1);
      lpair[pos] = make_uint2((uint)es[i], (uint)ed[i]);
    }
  }
  __syncthreads();

  const int total = hincl[255];
  for (int i = t; i < total; i += 256) {
    uint2 p = lpair[i];
    int bb = (int)(p.y >> BSH);    // bucket id directly from dst
    int lb = bb ? hincl[bb - 1] : 0;
    pairs[(size_t)hbase[bb] + (i - lb)] = p;
  }
}

// ---- fill2: one block per bucket, single-pass via LDS pair staging.
//      Computes its segment bounds locally from btot; counts its 512 nodes,
//      scans, writes offsets, scatters csr with LDS cursors. ----
__global__ __launch_bounds__(512) void fill2(const uint2* __restrict__ pairs,
                                             const int* __restrict__ btot,
                                             int* __restrict__ offsets,
                                             int* __restrict__ csr) {
  __shared__ uint2 lp[FMAX];       // 80 KB staged pairs
  __shared__ int cnt[512];
  __shared__ int cur[512];
  __shared__ int sdb[256];         // btot inclusive scan
  const int t = threadIdx.x;
  const int b = blockIdx.x;
  const int v0 = b << BSH;

  cnt[t] = 0;
  if (t < 256) sdb[t] = (t < NB) ? btot[t] : 0;
  __syncthreads();
  for (int off = 1; off < 256; off <<= 1) {
    int v = 0;
    if (t < 256 && t >= off) v = sdb[t - off];
    __syncthreads();
    if (t < 256 && t >= off) sdb[t] += v;
    __syncthreads();
  }
  const int pbeg = b ? sdb[b - 1] : 0;
  const int pend = sdb[b];
  const int m = pend - pbeg;
  const bool stage = (m <= FMAX);

  if (stage) {
    for (int j = t; j < m; j += 512) lp[j] = pairs[pbeg + j];
    __syncthreads();
    for (int j = t; j < m; j += 512)
      atomicAdd(&cnt[(int)lp[j].y - v0], 1);
  } else {
    for (int j = pbeg + t; j < pend; j += 512)
      atomicAdd(&cnt[(int)pairs[j].y - v0], 1);
  }
  __syncthreads();
  const int my = cnt[t];
  cur[t] = my;
  __syncthreads();
  for (int off = 1; off < 512; off <<= 1) {
    int v = 0;
    if (t >= off) v = cur[t - off];
    __syncthreads();
    if (t >= off) cur[t] += v;
    __syncthreads();
  }
  const int goff = pbeg + cur[t] - my;
  const int v = v0 + t;
  if (v < NN) offsets[v] = goff;
  if (b == 0 && t == 0) offsets[NN] = EE;
  __syncthreads();
  cur[t] = goff;
  __syncthreads();
  if (stage) {
    for (int j = t; j < m; j += 512) {
      uint2 p = lp[j];
      int pos = atomicAdd(&cur[(int)p.y - v0], 1);
      csr[pos] = (int)p.x;
    }
  } else {
    for (int j = pbeg + t; j < pend; j += 512) {
      uint2 p = pairs[j];
      int pos = atomicAdd(&cur[(int)p.y - v0], 1);
      csr[pos] = (int)p.x;
    }
  }
}

// ---------------- gather-reduce (bf16 rows -> bf16 rows) ----------------
// proven version: unroll-4, VGPR 24, occupancy ~69% — at the random-256B wall
__global__ __launch_bounds__(256) void gather_bf16(const uint4* __restrict__ feat,
                                                   const int* __restrict__ offsets,
                                                   const int* __restrict__ csr,
                                                   ushort* __restrict__ out) {
  int t = blockIdx.x * 256 + threadIdx.x;
  int g = t >> 4;
  int l = t & 15;
  if (g >= NN) return;
  int beg = offsets[g];
  int end = offsets[g + 1];
  float acc[8] = {};
  acc8(acc, feat[(size_t)g * 16 + l]);           // self term
  int j = beg;
  for (; j + 4 <= end; j += 4) {
    int i0 = csr[j], i1 = csr[j + 1], i2 = csr[j + 2], i3 = csr[j + 3];
    uint4 v0 = feat[(size_t)i0 * 16 + l];
    uint4 v1 = feat[(size_t)i1 * 16 + l];
    uint4 v2 = feat[(size_t)i2 * 16 + l];
    uint4 v3 = feat[(size_t)i3 * 16 + l];
    acc8(acc, v0); acc8(acc, v1); acc8(acc, v2); acc8(acc, v3);
  }
  for (; j < end; ++j) acc8(acc, feat[(size_t)csr[j] * 16 + l]);
  uint4 o;
  o.x = pack2(acc[0], acc[1]);
  o.y = pack2(acc[2], acc[3]);
  o.z = pack2(acc[4], acc[5]);
  o.w = pack2(acc[6], acc[7]);
  ((uint4*)(out + (size_t)g * FF))[l] = o;
}

// ---------------- bf16 MFMA GEMM (no LDS) ----------------
template <bool BN, bool OUT16>
__global__ __launch_bounds__(256) void gemm_mfma(const ushort* __restrict__ a,
    const ushort* __restrict__ bt, const float* __restrict__ bias,
    const float* __restrict__ gamma, const float* __restrict__ beta,
    const float* __restrict__ rmean, const float* __restrict__ rvar,
    void* __restrict__ out0, int nrows)
{
  const int tid = threadIdx.x;
  const int wv = tid >> 6;
  const int l = tid & 63;
  const int lane16 = l & 15;
  const int quad = l >> 4;
  const int rowbase = blockIdx.x * 128 + wv * 32;

  f32x4 acc[2][8] = {};

  for (int kc = 0; kc < FF; kc += 32) {
    short8 af[2];
#pragma unroll
    for (int rt = 0; rt < 2; ++rt) {
      int r = min(rowbase + rt * 16 + lane16, nrows - 1);
      af[rt] = *(const short8*)(a + (size_t)r * FF + kc + quad * 8);
    }
#pragma unroll
    for (int ct = 0; ct < 8; ++ct) {
      int n = ct * 16 + lane16;
      short8 bf = *(const short8*)(bt + n * FF + kc + quad * 8);
      acc[0][ct] = __builtin_amdgcn_mfma_f32_16x16x32_bf16(af[0], bf, acc[0][ct], 0, 0, 0);
      acc[1][ct] = __builtin_amdgcn_mfma_f32_16x16x32_bf16(af[1], bf, acc[1][ct], 0, 0, 0);
    }
  }

  float sc[8], sh[8];
#pragma unroll
  for (int ct = 0; ct < 8; ++ct) {
    int c = ct * 16 + lane16;
    if (BN) {
      float s = gamma[c] * rsqrtf(rvar[c] + 1e-5f);
      sc[ct] = s;
      sh[ct] = (bias[c] - rmean[c]) * s + beta[c];
    } else {
      sc[ct] = 1.0f;
      sh[ct] = bias[c];
    }
  }

#pragma unroll
  for (int rt = 0; rt < 2; ++rt) {
#pragma unroll
    for (int reg = 0; reg < 4; ++reg) {
      int r = rowbase + rt * 16 + quad * 4 + reg;
      if (r < nrows) {
#pragma unroll
        for (int ct = 0; ct < 8; ++ct) {
          int c = ct * 16 + lane16;
          float v = fmaf(acc[rt][ct][reg], sc[ct], sh[ct]);
          if (BN) v = fmaxf(v, 0.0f);
          if (OUT16) ((ushort*)out0)[(size_t)r * FF + c] = f2bf(v);
          else       ((float*)out0)[(size_t)r * FF + c] = v;
        }
      }
    }
  }
}

extern "C" void kernel_launch(void* const* d_in, const int* in_sizes, int n_in,
                              void* d_out, int out_size, void* d_ws, size_t ws_size,
                              hipStream_t stream) {
  const float* x     = (const float*)d_in[0];
  const int*   ei    = (const int*)d_in[1];
  const float* w0    = (const float*)d_in[2];
  const float* b0    = (const float*)d_in[3];
  const float* gamma = (const float*)d_in[4];
  const float* beta  = (const float*)d_in[5];
  const float* rmean = (const float*)d_in[6];
  const float* rvar  = (const float*)d_in[7];
  const float* w1    = (const float*)d_in[8];
  const float* b1    = (const float*)d_in[9];
  float* out = (float*)d_out;

  // workspace layout
  ushort* sb  = (ushort*)d_ws;                    // NN*FF
  ushort* xb  = sb + (size_t)NN * FF;             // NN*FF
  ushort* hb  = xb + (size_t)NN * FF;             // NN*FF
  ushort* wt0 = hb + (size_t)NN * FF;             // 128*128
  ushort* wt1 = wt0 + FF * FF;                    // 128*128
  uint2* pairs  = (uint2*)(wt1 + FF * FF);        // EE uint2 (12.8 MB)
  int* csr      = (int*)(pairs + (size_t)EE);     // EE
  int* offsets  = csr + EE;                       // NN+1
  int* btot     = offsets + NN + 1;               // NB
  int* bcur     = btot + NB;                      // NB (adjacent: one memset)

  const int gatherb = (NN * 16 + 255) / 256;      // 6250
  const int gemmb = (NN + 127) / 128;             // 782
  const int histb = (EE + HEPB - 1) / HEPB;       // 391
  const int bcb = BINB + XCB + WCB;               // 7160

  // ---- CSR build with converts overlapped ----
  (void)hipMemsetAsync(btot, 0, (size_t)(2 * NB) * sizeof(int), stream);
  bucket_hist<<<histb, 256, 0, stream>>>(ei, btot);
  bin_cvt<<<bcb, 256, 0, stream>>>(ei, btot, bcur, pairs,
                                   (const float4*)x, (uint4*)xb,
                                   w0, wt0, w1, wt1);
  fill2<<<NB, 512, 0, stream>>>(pairs, btot, offsets, csr);

  // ---- layer 1 ----
  gather_bf16<<<gatherb, 256, 0, stream>>>((const uint4*)xb, offsets, csr, sb);
  gemm_mfma<true, true><<<gemmb, 256, 0, stream>>>(sb, wt0, b0, gamma, beta,
                                                   rmean, rvar, (void*)hb, NN);
  // ---- layer 2 ----
  gather_bf16<<<gatherb, 256, 0, stream>>>((const uint4*)hb, offsets, csr, sb);
  gemm_mfma<false, false><<<gemmb, 256, 0, stream>>>(sb, wt1, b1, nullptr, nullptr,
                                                     nullptr, nullptr, (void*)out, NN);
}

// Round 9
// 327.688 us; speedup vs baseline: 1.2265x; 1.0717x over previous
//
#include <hip/hip_runtime.h>
#include <cstddef>

#define NN 100000
#define EE 1600000
#define FF 128
#define BSH 9                        // 512 nodes per bucket
#define NB ((NN + 511) / 512)        // 196 buckets
#define EPB 2048                     // edges per binscatter block (782 blocks)
#define HEPB 4096                    // edges per hist block (391 hist blocks)
#define FMAX 10240                   // fill2 LDS staging cap (mean 8192, +4sigma ~8550)
#define BINB 782                     // binscatter blocks
#define XCB 6250                     // x-convert blocks
#define WCB 128                      // w-convert blocks

typedef unsigned int uint;
typedef unsigned short ushort;
typedef short short8 __attribute__((ext_vector_type(8)));
typedef float f32x4 __attribute__((ext_vector_type(4)));

__device__ __forceinline__ ushort f2bf(float f) {
  uint u = __float_as_uint(f);
  uint r = u + 0x7fffu + ((u >> 16) & 1u);   // RNE
  return (ushort)(r >> 16);
}
__device__ __forceinline__ uint pack2(float a, float b) {
  return (uint)f2bf(a) | ((uint)f2bf(b) << 16);
}
// accumulate 8 bf16 (one uint4) into 8 fp32
__device__ __forceinline__ void acc8(float* a, uint4 v) {
  a[0] += __uint_as_float(v.x << 16);
  a[1] += __uint_as_float(v.x & 0xffff0000u);
  a[2] += __uint_as_float(v.y << 16);
  a[3] += __uint_as_float(v.y & 0xffff0000u);
  a[4] += __uint_as_float(v.z << 16);
  a[5] += __uint_as_float(v.z & 0xffff0000u);
  a[6] += __uint_as_float(v.w << 16);
  a[7] += __uint_as_float(v.w & 0xffff0000u);
}

// ---------------- bucket histogram (196 bins, LDS-privatized) ----------------
__global__ __launch_bounds__(256) void bucket_hist(const int* __restrict__ ei,
                                                   int* __restrict__ btot) {
  __shared__ int h[NB];
  const int t = threadIdx.x;
  for (int i = t; i < NB; i += 256) h[i] = 0;
  __syncthreads();
  const int e0 = blockIdx.x * HEPB + t;
#pragma unroll
  for (int i = 0; i < 16; ++i) {
    int e = e0 + i * 256;
    if (e < EE) atomicAdd(&h[ei[EE + e] >> BSH], 1);
  }
  __syncthreads();
  for (int i = t; i < NB; i += 256)
    if (h[i]) atomicAdd(&btot[i], h[i]);
}

// ---- bin_cvt: heterogeneous grid ----
// blocks 0..781       : binscatter (CSR critical path, dispatched first)
// blocks 782..7031    : x -> bf16 convert (overlaps binscatter)
// blocks 7032..7159   : w0/w1 transpose-convert
__global__ __launch_bounds__(256) void bin_cvt(const int* __restrict__ ei,
                                               const int* __restrict__ btot,
                                               int* __restrict__ bcur,
                                               uint2* __restrict__ pairs,
                                               const float4* __restrict__ x,
                                               uint4* __restrict__ xb,
                                               const float* __restrict__ w0,
                                               ushort* __restrict__ wt0,
                                               const float* __restrict__ w1,
                                               ushort* __restrict__ wt1) {
  __shared__ uint2 lpair[EPB];     // 16 KB
  __shared__ int hcnt[256];        // hist, then local scatter cursor
  __shared__ int hincl[256];       // inclusive scan over buckets
  __shared__ int hbase[256];       // global base per bucket
  __shared__ int sdb[256];         // btot inclusive scan
  const int b = blockIdx.x;
  const int t = threadIdx.x;

  if (b >= BINB) {
    if (b < BINB + XCB) {
      int i = (b - BINB) * 256 + t;
      if (i < NN * FF / 8) {
        float4 a = x[2 * i];
        float4 c = x[2 * i + 1];
        uint4 o;
        o.x = pack2(a.x, a.y);
        o.y = pack2(a.z, a.w);
        o.z = pack2(c.x, c.y);
        o.w = pack2(c.z, c.w);
        xb[i] = o;
      }
    } else {
      int i = (b - BINB - XCB) * 256 + t;     // 0..32767
      const float* w = (i < 16384) ? w0 : w1;
      ushort* wt = (i < 16384) ? wt0 : wt1;
      int j = i & 16383;
      int k = j >> 7, n = j & 127;
      wt[n * FF + k] = f2bf(w[(size_t)k * FF + n]);
    }
    return;
  }

  // ---------------- binscatter part (blocks 0..781) ----------------
  const int e0 = b * EPB;
  hcnt[t] = 0;
  sdb[t] = (t < NB) ? btot[t] : 0;
  __syncthreads();

  int es[8], ed[8];
#pragma unroll
  for (int i = 0; i < 8; ++i) {
    int e = e0 + t + i * 256;
    if (e < EE) {
      es[i] = ei[e];
      ed[i] = ei[EE + e];
      atomicAdd(&hcnt[ed[i] >> BSH], 1);
    } else {
      es[i] = -1;
      ed[i] = 0;
    }
  }
  // btot scan (dependency-free vs the staging loads above)
  for (int off = 1; off < 256; off <<= 1) {
    int v = 0;
    if (t >= off) v = sdb[t - off];
    __syncthreads();
    if (t >= off) sdb[t] += v;
    __syncthreads();
  }
  __syncthreads();

  const int mycnt = hcnt[t];
  hincl[t] = mycnt;
  __syncthreads();
  for (int off = 1; off < 256; off <<= 1) {
    int tv = 0;
    if (t >= off) tv = hincl[t - off];
    __syncthreads();
    if (t >= off) hincl[t] += tv;
    __syncthreads();
  }
  // reserve global range: local base from btot scan + delta cursor
  if (t < NB && mycnt > 0) {
    int gbase = t ? sdb[t - 1] : 0;
    hbase[t] = gbase + atomicAdd(&bcur[t], mycnt);
  }
  const int lbase = hincl[t] - mycnt;
  __syncthreads();
  hcnt[t] = lbase;                 // becomes local scatter cursor
  __syncthreads();

#pragma unroll
  for (int i = 0; i < 8; ++i) {
    if (es[i] >= 0) {
      int bb = ed[i] >> BSH;
      int pos = atomicAdd(&hcnt[bb], 1);
      lpair[pos] = make_uint2((uint)es[i], (uint)ed[i]);
    }
  }
  __syncthreads();

  const int total = hincl[255];
  for (int i = t; i < total; i += 256) {
    uint2 p = lpair[i];
    int bb = (int)(p.y >> BSH);    // bucket id directly from dst
    int lb = bb ? hincl[bb - 1] : 0;
    pairs[(size_t)hbase[bb] + (i - lb)] = p;
  }
}

// ---- fill2: one block per bucket, single-pass via LDS pair staging ----
__global__ __launch_bounds__(512) void fill2(const uint2* __restrict__ pairs,
                                             const int* __restrict__ btot,
                                             int* __restrict__ offsets,
                                             int* __restrict__ csr) {
  __shared__ uint2 lp[FMAX];       // 80 KB staged pairs
  __shared__ int cnt[512];
  __shared__ int cur[512];
  __shared__ int sdb[256];         // btot inclusive scan
  const int t = threadIdx.x;
  const int b = blockIdx.x;
  const int v0 = b << BSH;

  cnt[t] = 0;
  if (t < 256) sdb[t] = (t < NB) ? btot[t] : 0;
  __syncthreads();
  for (int off = 1; off < 256; off <<= 1) {
    int v = 0;
    if (t < 256 && t >= off) v = sdb[t - off];
    __syncthreads();
    if (t < 256 && t >= off) sdb[t] += v;
    __syncthreads();
  }
  const int pbeg = b ? sdb[b - 1] : 0;
  const int pend = sdb[b];
  const int m = pend - pbeg;
  const bool stage = (m <= FMAX);

  if (stage) {
    for (int j = t; j < m; j += 512) lp[j] = pairs[pbeg + j];
    __syncthreads();
    for (int j = t; j < m; j += 512)
      atomicAdd(&cnt[(int)lp[j].y - v0], 1);
  } else {
    for (int j = pbeg + t; j < pend; j += 512)
      atomicAdd(&cnt[(int)pairs[j].y - v0], 1);
  }
  __syncthreads();
  const int my = cnt[t];
  cur[t] = my;
  __syncthreads();
  for (int off = 1; off < 512; off <<= 1) {
    int v = 0;
    if (t >= off) v = cur[t - off];
    __syncthreads();
    if (t >= off) cur[t] += v;
    __syncthreads();
  }
  const int goff = pbeg + cur[t] - my;
  const int v = v0 + t;
  if (v < NN) offsets[v] = goff;
  if (b == 0 && t == 0) offsets[NN] = EE;
  __syncthreads();
  cur[t] = goff;
  __syncthreads();
  if (stage) {
    for (int j = t; j < m; j += 512) {
      uint2 p = lp[j];
      int pos = atomicAdd(&cur[(int)p.y - v0], 1);
      csr[pos] = (int)p.x;
    }
  } else {
    for (int j = pbeg + t; j < pend; j += 512) {
      uint2 p = pairs[j];
      int pos = atomicAdd(&cur[(int)p.y - v0], 1);
      csr[pos] = (int)p.x;
    }
  }
}

// -------- fused gather + GEMM, gather geometry PRESERVED --------
// 6250 blocks x 256 threads; 16-lane group = 1 row, lane = one 16B column
// slice — byte-identical gather memory behavior to the proven standalone
// kernel (round-3's failure reshaped this; here it is untouched).
// NN = 6250*16 exactly -> no row guards.
// Tail: 16 gathered rows -> 4.3 KB padded LDS tile ([16][17] uint4: 2-way
// banks = free), one barrier, each wave does a 16x32 output slice
// (8 MFMAs, A from LDS, B from the L2-hot 32KB wt). Removes the sb
// round-trip (50 MB/layer) and one dispatch per layer.
template <bool BN, bool OUT16>
__global__ __launch_bounds__(256) void gather_gemm(const uint4* __restrict__ feat,
    const int* __restrict__ offsets, const int* __restrict__ csr,
    const ushort* __restrict__ bt, const float* __restrict__ bias,
    const float* __restrict__ gamma, const float* __restrict__ beta,
    const float* __restrict__ rmean, const float* __restrict__ rvar,
    void* __restrict__ out0)
{
  __shared__ uint4 As[16][17];     // 16 rows x 128 bf16, +1 uint4 pad

  const int t = threadIdx.x;
  const int rloc = t >> 4;         // block-local row 0..15
  const int l = t & 15;            // 16B column slice
  const int g0 = blockIdx.x * 16;
  const int g = g0 + rloc;

  // ---- gather phase (identical to proven gather_bf16) ----
  {
    int beg = offsets[g];
    int end = offsets[g + 1];
    float acc[8] = {};
    acc8(acc, feat[(size_t)g * 16 + l]);         // self term
    int j = beg;
    for (; j + 4 <= end; j += 4) {
      int i0 = csr[j], i1 = csr[j + 1], i2 = csr[j + 2], i3 = csr[j + 3];
      uint4 v0 = feat[(size_t)i0 * 16 + l];
      uint4 v1 = feat[(size_t)i1 * 16 + l];
      uint4 v2 = feat[(size_t)i2 * 16 + l];
      uint4 v3 = feat[(size_t)i3 * 16 + l];
      acc8(acc, v0); acc8(acc, v1); acc8(acc, v2); acc8(acc, v3);
    }
    for (; j < end; ++j) acc8(acc, feat[(size_t)csr[j] * 16 + l]);
    uint4 o;
    o.x = pack2(acc[0], acc[1]);
    o.y = pack2(acc[2], acc[3]);
    o.z = pack2(acc[4], acc[5]);
    o.w = pack2(acc[6], acc[7]);
    As[rloc][l] = o;
  }
  __syncthreads();

  // ---- GEMM tail: wave wv -> column-tiles ct = 2wv, 2wv+1 ----
  const int wv = t >> 6;
  const int l64 = t & 63;
  const int lane16 = l64 & 15;
  const int quad = l64 >> 4;

  f32x4 cacc[2] = {};
  for (int kc = 0; kc < FF; kc += 32) {
    short8 af = *(const short8*)&As[lane16][(kc >> 3) + quad];
#pragma unroll
    for (int ci = 0; ci < 2; ++ci) {
      int n = (wv * 2 + ci) * 16 + lane16;
      short8 bf = *(const short8*)(bt + n * FF + kc + quad * 8);
      cacc[ci] = __builtin_amdgcn_mfma_f32_16x16x32_bf16(af, bf, cacc[ci], 0, 0, 0);
    }
  }

  float sc[2], sh[2];
#pragma unroll
  for (int ci = 0; ci < 2; ++ci) {
    int c = (wv * 2 + ci) * 16 + lane16;
    if (BN) {
      float s = gamma[c] * rsqrtf(rvar[c] + 1e-5f);
      sc[ci] = s;
      sh[ci] = (bias[c] - rmean[c]) * s + beta[c];
    } else {
      sc[ci] = 1.0f;
      sh[ci] = bias[c];
    }
  }

#pragma unroll
  for (int ci = 0; ci < 2; ++ci) {
    int c = (wv * 2 + ci) * 16 + lane16;
#pragma unroll
    for (int reg = 0; reg < 4; ++reg) {
      int r = g0 + quad * 4 + reg;
      float v = fmaf(cacc[ci][reg], sc[ci], sh[ci]);
      if (BN) v = fmaxf(v, 0.0f);
      if (OUT16) ((ushort*)out0)[(size_t)r * FF + c] = f2bf(v);
      else       ((float*)out0)[(size_t)r * FF + c] = v;
    }
  }
}

extern "C" void kernel_launch(void* const* d_in, const int* in_sizes, int n_in,
                              void* d_out, int out_size, void* d_ws, size_t ws_size,
                              hipStream_t stream) {
  const float* x     = (const float*)d_in[0];
  const int*   ei    = (const int*)d_in[1];
  const float* w0    = (const float*)d_in[2];
  const float* b0    = (const float*)d_in[3];
  const float* gamma = (const float*)d_in[4];
  const float* beta  = (const float*)d_in[5];
  const float* rmean = (const float*)d_in[6];
  const float* rvar  = (const float*)d_in[7];
  const float* w1    = (const float*)d_in[8];
  const float* b1    = (const float*)d_in[9];
  float* out = (float*)d_out;

  // workspace layout (sb slot retained but unused)
  ushort* sb  = (ushort*)d_ws;                    // NN*FF (unused)
  ushort* xb  = sb + (size_t)NN * FF;             // NN*FF
  ushort* hb  = xb + (size_t)NN * FF;             // NN*FF
  ushort* wt0 = hb + (size_t)NN * FF;             // 128*128
  ushort* wt1 = wt0 + FF * FF;                    // 128*128
  uint2* pairs  = (uint2*)(wt1 + FF * FF);        // EE uint2 (12.8 MB)
  int* csr      = (int*)(pairs + (size_t)EE);     // EE
  int* offsets  = csr + EE;                       // NN+1
  int* btot     = offsets + NN + 1;               // NB
  int* bcur     = btot + NB;                      // NB (adjacent: one memset)

  const int ggb = NN / 16;                        // 6250 (exact)
  const int histb = (EE + HEPB - 1) / HEPB;       // 391
  const int bcb = BINB + XCB + WCB;               // 7160

  // ---- CSR build with converts overlapped ----
  (void)hipMemsetAsync(btot, 0, (size_t)(2 * NB) * sizeof(int), stream);
  bucket_hist<<<histb, 256, 0, stream>>>(ei, btot);
  bin_cvt<<<bcb, 256, 0, stream>>>(ei, btot, bcur, pairs,
                                   (const float4*)x, (uint4*)xb,
                                   w0, wt0, w1, wt1);
  fill2<<<NB, 512, 0, stream>>>(pairs, btot, offsets, csr);

  // ---- layer 1: fused gather+GEMM+BN+ReLU -> bf16 hb ----
  gather_gemm<true, true><<<ggb, 256, 0, stream>>>((const uint4*)xb, offsets, csr,
      wt0, b0, gamma, beta, rmean, rvar, (void*)hb);
  // ---- layer 2: fused gather+GEMM -> f32 out ----
  gather_gemm<false, false><<<ggb, 256, 0, stream>>>((const uint4*)hb, offsets, csr,
      wt1, b1, nullptr, nullptr, nullptr, nullptr, (void*)out);
}

// Round 10
// 323.320 us; speedup vs baseline: 1.2431x; 1.0135x over previous
//
#include <hip/hip_runtime.h>
#include <cstddef>

#define NN 100000
#define EE 1600000
#define FF 128
#define BSH 9                        // 512 nodes per bucket
#define NB ((NN + 511) / 512)        // 196 buckets
#define EPB 2048                     // edges per binscatter block (782 blocks)
#define HEPB 4096                    // edges per hist block (391 hist blocks)
#define FMAX 10240                   // fill2 LDS staging cap (mean 8192, +4sigma ~8550)
#define BINB 782                     // binscatter blocks
#define XCB 6250                     // x-convert blocks
#define WCB 128                      // w-convert blocks

typedef unsigned int uint;
typedef unsigned short ushort;
typedef short short8 __attribute__((ext_vector_type(8)));
typedef float f32x4 __attribute__((ext_vector_type(4)));

__device__ __forceinline__ ushort f2bf(float f) {
  uint u = __float_as_uint(f);
  uint r = u + 0x7fffu + ((u >> 16) & 1u);   // RNE
  return (ushort)(r >> 16);
}
__device__ __forceinline__ uint pack2(float a, float b) {
  return (uint)f2bf(a) | ((uint)f2bf(b) << 16);
}
// accumulate 8 bf16 (one uint4) into 8 fp32
__device__ __forceinline__ void acc8(float* a, uint4 v) {
  a[0] += __uint_as_float(v.x << 16);
  a[1] += __uint_as_float(v.x & 0xffff0000u);
  a[2] += __uint_as_float(v.y << 16);
  a[3] += __uint_as_float(v.y & 0xffff0000u);
  a[4] += __uint_as_float(v.z << 16);
  a[5] += __uint_as_float(v.z & 0xffff0000u);
  a[6] += __uint_as_float(v.w << 16);
  a[7] += __uint_as_float(v.w & 0xffff0000u);
}

// ---------------- bucket histogram (196 bins, LDS-privatized) ----------------
__global__ __launch_bounds__(256) void bucket_hist(const int* __restrict__ ei,
                                                   int* __restrict__ btot) {
  __shared__ int h[NB];
  const int t = threadIdx.x;
  for (int i = t; i < NB; i += 256) h[i] = 0;
  __syncthreads();
  const int e0 = blockIdx.x * HEPB + t;
#pragma unroll
  for (int i = 0; i < 16; ++i) {
    int e = e0 + i * 256;
    if (e < EE) atomicAdd(&h[ei[EE + e] >> BSH], 1);
  }
  __syncthreads();
  for (int i = t; i < NB; i += 256)
    if (h[i]) atomicAdd(&btot[i], h[i]);
}

// ---- bin_cvt: heterogeneous grid ----
// blocks 0..781       : binscatter (CSR critical path, dispatched first)
// blocks 782..7031    : x -> bf16 convert (overlaps binscatter)
// blocks 7032..7159   : w0/w1 transpose-convert
__global__ __launch_bounds__(256) void bin_cvt(const int* __restrict__ ei,
                                               const int* __restrict__ btot,
                                               int* __restrict__ bcur,
                                               uint2* __restrict__ pairs,
                                               const float4* __restrict__ x,
                                               uint4* __restrict__ xb,
                                               const float* __restrict__ w0,
                                               ushort* __restrict__ wt0,
                                               const float* __restrict__ w1,
                                               ushort* __restrict__ wt1) {
  __shared__ uint2 lpair[EPB];     // 16 KB
  __shared__ int hcnt[256];        // hist, then local scatter cursor
  __shared__ int hincl[256];       // inclusive scan over buckets
  __shared__ int hbase[256];       // global base per bucket
  __shared__ int sdb[256];         // btot inclusive scan
  const int b = blockIdx.x;
  const int t = threadIdx.x;

  if (b >= BINB) {
    if (b < BINB + XCB) {
      int i = (b - BINB) * 256 + t;
      if (i < NN * FF / 8) {
        float4 a = x[2 * i];
        float4 c = x[2 * i + 1];
        uint4 o;
        o.x = pack2(a.x, a.y);
        o.y = pack2(a.z, a.w);
        o.z = pack2(c.x, c.y);
        o.w = pack2(c.z, c.w);
        xb[i] = o;
      }
    } else {
      int i = (b - BINB - XCB) * 256 + t;     // 0..32767
      const float* w = (i < 16384) ? w0 : w1;
      ushort* wt = (i < 16384) ? wt0 : wt1;
      int j = i & 16383;
      int k = j >> 7, n = j & 127;
      wt[n * FF + k] = f2bf(w[(size_t)k * FF + n]);
    }
    return;
  }

  // ---------------- binscatter part (blocks 0..781) ----------------
  const int e0 = b * EPB;
  hcnt[t] = 0;
  sdb[t] = (t < NB) ? btot[t] : 0;
  __syncthreads();

  int es[8], ed[8];
#pragma unroll
  for (int i = 0; i < 8; ++i) {
    int e = e0 + t + i * 256;
    if (e < EE) {
      es[i] = ei[e];
      ed[i] = ei[EE + e];
      atomicAdd(&hcnt[ed[i] >> BSH], 1);
    } else {
      es[i] = -1;
      ed[i] = 0;
    }
  }
  // btot scan (dependency-free vs the staging loads above)
  for (int off = 1; off < 256; off <<= 1) {
    int v = 0;
    if (t >= off) v = sdb[t - off];
    __syncthreads();
    if (t >= off) sdb[t] += v;
    __syncthreads();
  }
  __syncthreads();

  const int mycnt = hcnt[t];
  hincl[t] = mycnt;
  __syncthreads();
  for (int off = 1; off < 256; off <<= 1) {
    int tv = 0;
    if (t >= off) tv = hincl[t - off];
    __syncthreads();
    if (t >= off) hincl[t] += tv;
    __syncthreads();
  }
  // reserve global range: local base from btot scan + delta cursor
  if (t < NB && mycnt > 0) {
    int gbase = t ? sdb[t - 1] : 0;
    hbase[t] = gbase + atomicAdd(&bcur[t], mycnt);
  }
  const int lbase = hincl[t] - mycnt;
  __syncthreads();
  hcnt[t] = lbase;                 // becomes local scatter cursor
  __syncthreads();

#pragma unroll
  for (int i = 0; i < 8; ++i) {
    if (es[i] >= 0) {
      int bb = ed[i] >> BSH;
      int pos = atomicAdd(&hcnt[bb], 1);
      lpair[pos] = make_uint2((uint)es[i], (uint)ed[i]);
    }
  }
  __syncthreads();

  const int total = hincl[255];
  for (int i = t; i < total; i += 256) {
    uint2 p = lpair[i];
    int bb = (int)(p.y >> BSH);    // bucket id directly from dst
    int lb = bb ? hincl[bb - 1] : 0;
    pairs[(size_t)hbase[bb] + (i - lb)] = p;
  }
}

// ---- fill2: one block per bucket, single-pass via LDS pair staging ----
__global__ __launch_bounds__(512) void fill2(const uint2* __restrict__ pairs,
                                             const int* __restrict__ btot,
                                             int* __restrict__ offsets,
                                             int* __restrict__ csr) {
  __shared__ uint2 lp[FMAX];       // 80 KB staged pairs
  __shared__ int cnt[512];
  __shared__ int cur[512];
  __shared__ int sdb[256];         // btot inclusive scan
  const int t = threadIdx.x;
  const int b = blockIdx.x;
  const int v0 = b << BSH;

  cnt[t] = 0;
  if (t < 256) sdb[t] = (t < NB) ? btot[t] : 0;
  __syncthreads();
  for (int off = 1; off < 256; off <<= 1) {
    int v = 0;
    if (t < 256 && t >= off) v = sdb[t - off];
    __syncthreads();
    if (t < 256 && t >= off) sdb[t] += v;
    __syncthreads();
  }
  const int pbeg = b ? sdb[b - 1] : 0;
  const int pend = sdb[b];
  const int m = pend - pbeg;
  const bool stage = (m <= FMAX);

  if (stage) {
    for (int j = t; j < m; j += 512) lp[j] = pairs[pbeg + j];
    __syncthreads();
    for (int j = t; j < m; j += 512)
      atomicAdd(&cnt[(int)lp[j].y - v0], 1);
  } else {
    for (int j = pbeg + t; j < pend; j += 512)
      atomicAdd(&cnt[(int)pairs[j].y - v0], 1);
  }
  __syncthreads();
  const int my = cnt[t];
  cur[t] = my;
  __syncthreads();
  for (int off = 1; off < 512; off <<= 1) {
    int v = 0;
    if (t >= off) v = cur[t - off];
    __syncthreads();
    if (t >= off) cur[t] += v;
    __syncthreads();
  }
  const int goff = pbeg + cur[t] - my;
  const int v = v0 + t;
  if (v < NN) offsets[v] = goff;
  if (b == 0 && t == 0) offsets[NN] = EE;
  __syncthreads();
  cur[t] = goff;
  __syncthreads();
  if (stage) {
    for (int j = t; j < m; j += 512) {
      uint2 p = lp[j];
      int pos = atomicAdd(&cur[(int)p.y - v0], 1);
      csr[pos] = (int)p.x;
    }
  } else {
    for (int j = pbeg + t; j < pend; j += 512) {
      uint2 p = pairs[j];
      int pos = atomicAdd(&cur[(int)p.y - v0], 1);
      csr[pos] = (int)p.x;
    }
  }
}

// -------- fused gather + GEMM, gather geometry PRESERVED, tail pipelined ----
// 6250 blocks x 256 threads; 16-lane group = 1 row, lane = one 16B column
// slice — byte-identical gather memory behavior to the proven standalone
// kernel. NN = 6250*16 exactly -> no row guards.
// Pipelining (this round): all tail work that does NOT depend on the LDS
// A-tile (8 B-fragment loads from L2-hot wt, BN scale/shift) is issued
// BEFORE __syncthreads, so its ~200-400cy latency overlaps the barrier's
// straggler wait instead of following it. Post-barrier: 8 ds_read_b128 +
// 8 MFMA + epilogue only.
template <bool BN, bool OUT16>
__global__ __launch_bounds__(256) void gather_gemm(const uint4* __restrict__ feat,
    const int* __restrict__ offsets, const int* __restrict__ csr,
    const ushort* __restrict__ bt, const float* __restrict__ bias,
    const float* __restrict__ gamma, const float* __restrict__ beta,
    const float* __restrict__ rmean, const float* __restrict__ rvar,
    void* __restrict__ out0)
{
  __shared__ uint4 As[16][17];     // 16 rows x 128 bf16, +1 uint4 pad (2-way banks)

  const int t = threadIdx.x;
  const int rloc = t >> 4;         // block-local row 0..15
  const int l = t & 15;            // 16B column slice
  const int g0 = blockIdx.x * 16;
  const int g = g0 + rloc;

  // ---- gather phase (identical to proven gather_bf16) ----
  {
    int beg = offsets[g];
    int end = offsets[g + 1];
    float acc[8] = {};
    acc8(acc, feat[(size_t)g * 16 + l]);         // self term
    int j = beg;
    for (; j + 4 <= end; j += 4) {
      int i0 = csr[j], i1 = csr[j + 1], i2 = csr[j + 2], i3 = csr[j + 3];
      uint4 v0 = feat[(size_t)i0 * 16 + l];
      uint4 v1 = feat[(size_t)i1 * 16 + l];
      uint4 v2 = feat[(size_t)i2 * 16 + l];
      uint4 v3 = feat[(size_t)i3 * 16 + l];
      acc8(acc, v0); acc8(acc, v1); acc8(acc, v2); acc8(acc, v3);
    }
    for (; j < end; ++j) acc8(acc, feat[(size_t)csr[j] * 16 + l]);
    uint4 o;
    o.x = pack2(acc[0], acc[1]);
    o.y = pack2(acc[2], acc[3]);
    o.z = pack2(acc[4], acc[5]);
    o.w = pack2(acc[6], acc[7]);
    As[rloc][l] = o;
  }

  // ---- pre-barrier prefetch: B fragments + BN scale/shift (A-independent) ----
  const int wv = t >> 6;
  const int l64 = t & 63;
  const int lane16 = l64 & 15;
  const int quad = l64 >> 4;

  short8 bf[4][2];                 // [kc/32][ci] — static indices -> registers
#pragma unroll
  for (int kc4 = 0; kc4 < 4; ++kc4) {
#pragma unroll
    for (int ci = 0; ci < 2; ++ci) {
      int n = (wv * 2 + ci) * 16 + lane16;
      bf[kc4][ci] = *(const short8*)(bt + (size_t)n * FF + kc4 * 32 + quad * 8);
    }
  }
  float sc[2], sh[2];
#pragma unroll
  for (int ci = 0; ci < 2; ++ci) {
    int c = (wv * 2 + ci) * 16 + lane16;
    if (BN) {
      float s = gamma[c] * rsqrtf(rvar[c] + 1e-5f);
      sc[ci] = s;
      sh[ci] = (bias[c] - rmean[c]) * s + beta[c];
    } else {
      sc[ci] = 1.0f;
      sh[ci] = bias[c];
    }
  }

  __syncthreads();

  // ---- MFMA tail: 8 ds_read_b128 + 8 MFMA ----
  f32x4 cacc[2] = {};
#pragma unroll
  for (int kc4 = 0; kc4 < 4; ++kc4) {
    short8 af = *(const short8*)&As[lane16][kc4 * 4 + quad];
#pragma unroll
    for (int ci = 0; ci < 2; ++ci)
      cacc[ci] = __builtin_amdgcn_mfma_f32_16x16x32_bf16(af, bf[kc4][ci], cacc[ci], 0, 0, 0);
  }

#pragma unroll
  for (int ci = 0; ci < 2; ++ci) {
    int c = (wv * 2 + ci) * 16 + lane16;
#pragma unroll
    for (int reg = 0; reg < 4; ++reg) {
      int r = g0 + quad * 4 + reg;
      float v = fmaf(cacc[ci][reg], sc[ci], sh[ci]);
      if (BN) v = fmaxf(v, 0.0f);
      if (OUT16) ((ushort*)out0)[(size_t)r * FF + c] = f2bf(v);
      else       ((float*)out0)[(size_t)r * FF + c] = v;
    }
  }
}

extern "C" void kernel_launch(void* const* d_in, const int* in_sizes, int n_in,
                              void* d_out, int out_size, void* d_ws, size_t ws_size,
                              hipStream_t stream) {
  const float* x     = (const float*)d_in[0];
  const int*   ei    = (const int*)d_in[1];
  const float* w0    = (const float*)d_in[2];
  const float* b0    = (const float*)d_in[3];
  const float* gamma = (const float*)d_in[4];
  const float* beta  = (const float*)d_in[5];
  const float* rmean = (const float*)d_in[6];
  const float* rvar  = (const float*)d_in[7];
  const float* w1    = (const float*)d_in[8];
  const float* b1    = (const float*)d_in[9];
  float* out = (float*)d_out;

  // workspace layout (sb slot retained but unused)
  ushort* sb  = (ushort*)d_ws;                    // NN*FF (unused)
  ushort* xb  = sb + (size_t)NN * FF;             // NN*FF
  ushort* hb  = xb + (size_t)NN * FF;             // NN*FF
  ushort* wt0 = hb + (size_t)NN * FF;             // 128*128
  ushort* wt1 = wt0 + FF * FF;                    // 128*128
  uint2* pairs  = (uint2*)(wt1 + FF * FF);        // EE uint2 (12.8 MB)
  int* csr      = (int*)(pairs + (size_t)EE);     // EE
  int* offsets  = csr + EE;                       // NN+1
  int* btot     = offsets + NN + 1;               // NB
  int* bcur     = btot + NB;                      // NB (adjacent: one memset)

  const int ggb = NN / 16;                        // 6250 (exact)
  const int histb = (EE + HEPB - 1) / HEPB;       // 391
  const int bcb = BINB + XCB + WCB;               // 7160

  // ---- CSR build with converts overlapped ----
  (void)hipMemsetAsync(btot, 0, (size_t)(2 * NB) * sizeof(int), stream);
  bucket_hist<<<histb, 256, 0, stream>>>(ei, btot);
  bin_cvt<<<bcb, 256, 0, stream>>>(ei, btot, bcur, pairs,
                                   (const float4*)x, (uint4*)xb,
                                   w0, wt0, w1, wt1);
  fill2<<<NB, 512, 0, stream>>>(pairs, btot, offsets, csr);

  // ---- layer 1: fused gather+GEMM+BN+ReLU -> bf16 hb ----
  gather_gemm<true, true><<<ggb, 256, 0, stream>>>((const uint4*)xb, offsets, csr,
      wt0, b0, gamma, beta, rmean, rvar, (void*)hb);
  // ---- layer 2: fused gather+GEMM -> f32 out ----
  gather_gemm<false, false><<<ggb, 256, 0, stream>>>((const uint4*)hb, offsets, csr,
      wt1, b1, nullptr, nullptr, nullptr, nullptr, (void*)out);
}